// Round 12
// baseline (174.691 us; speedup 1.0000x reference)
//
#include <hip/hip_runtime.h>
#include <stdint.h>

#define NW   2048
#define OBS  512
#define HS   512
#define HS2  512
#define HM   256
#define CTX  128
#define ACT  18

#define K2LE 2.8853900817779268f   // 2*log2(e)

// ws layout (floats)
#define W1T_OFF   0          // [512 k][512 c]
#define WCT_OFF   262144     // [256 m][128 c]
#define W2T_OFF   294912     // [768 k][512 c]
#define WHHQ_OFF  688128     // [256 m][256 j] float4 (Wr,Wz,Wn,0)
#define FEAT_OFF  950272     // [2048][512]
#define GATES_OFF 1998848    // [2048][768]  (b_hh added)
#define HTERM_OFF 3571712    // [2048][128]  (K2LE-prescaled, bc added)
#define X_OFF     3833856    // [2048]
#define OUT2_OFF  3835904    // [2048][512]
// total 4,884,480 floats = 19.5 MB

#if __has_builtin(__builtin_amdgcn_exp2f)
#define EXP2F(x) __builtin_amdgcn_exp2f(x)
#else
#define EXP2F(x) exp2f(x)
#endif
#if __has_builtin(__builtin_amdgcn_rcpf)
#define RCPF(x) __builtin_amdgcn_rcpf(x)
#else
#define RCPF(x) (1.0f/(x))
#endif

// ---------------- threefry2x32 (key = (0,42)), 20 rounds ----------------
#define TFR(x0, x1, R) { x0 += x1; x1 = (x1 << R) | (x1 >> (32 - R)); x1 ^= x0; }

__device__ __forceinline__ void threefry_0_42(uint32_t x0, uint32_t x1,
                                              uint32_t& o0, uint32_t& o1) {
    const uint32_t ks0 = 0u;
    const uint32_t ks1 = 42u;
    const uint32_t ks2 = 0x1BD11BDAu ^ ks0 ^ ks1;
    x0 += ks0; x1 += ks1;
    TFR(x0, x1, 13) TFR(x0, x1, 15) TFR(x0, x1, 26) TFR(x0, x1, 6)
    x0 += ks1; x1 += ks2 + 1u;
    TFR(x0, x1, 17) TFR(x0, x1, 29) TFR(x0, x1, 16) TFR(x0, x1, 24)
    x0 += ks2; x1 += ks0 + 2u;
    TFR(x0, x1, 13) TFR(x0, x1, 15) TFR(x0, x1, 26) TFR(x0, x1, 6)
    x0 += ks0; x1 += ks1 + 3u;
    TFR(x0, x1, 17) TFR(x0, x1, 29) TFR(x0, x1, 16) TFR(x0, x1, 24)
    x0 += ks1; x1 += ks2 + 4u;
    TFR(x0, x1, 13) TFR(x0, x1, 15) TFR(x0, x1, 26) TFR(x0, x1, 6)
    x0 += ks2; x1 += ks0 + 5u;
    o0 = x0; o1 = x1;
}

// jax_threefry_partitionable scheme (verified round 2): counter=(0,n), out0^out1
__device__ __forceinline__ float gumbel_ra(int row, int a) {
    uint32_t n = (uint32_t)(row * ACT + a);
    uint32_t o0, o1;
    threefry_0_42(0u, n, o0, o1);
    uint32_t bits = o0 ^ o1;
    uint32_t fb = (bits >> 9) | 0x3F800000u;
    float f = __uint_as_float(fb) - 1.0f;
    const float tiny = 1.17549435e-38f;
    float u = (f < tiny) ? tiny : f;
    return -logf(-logf(u));
}

__device__ __forceinline__ float fast_tanh(float x) {
    float e = __expf(2.0f * x);
    return 1.0f - 2.0f / (e + 1.0f);
}
__device__ __forceinline__ float fast_sig(float x) {
    return 1.0f / (1.0f + __expf(-x));
}

// ---- weight prep: transposes + GRU gate-pack into ws ----
__global__ __launch_bounds__(256) void transpose_weights(
    const float* __restrict__ W1, const float* __restrict__ Wc,
    const float* __restrict__ Whh, const float* __restrict__ W2,
    float* __restrict__ ws)
{
    __shared__ float t[3][32][33];
    const int tx = threadIdx.x & 31, ty = threadIdx.x >> 5;   // 32 x 8
    int b = blockIdx.x;
    if (b < 672) {
        const float* src; float* dst; int ld, off, R, it, jt;
        if (b < 256)      { src = W1;  dst = ws + W1T_OFF;  ld = 512; off = 0; it = b >> 4; jt = b & 15; R = 512; }
        else if (b < 288) { int bb = b - 256; src = Wc;  dst = ws + WCT_OFF;  ld = 257; off = 1; it = bb >> 3; jt = bb & 7;  R = 128; }
        else              { int bb = b - 288; src = W2;  dst = ws + W2T_OFF;  ld = 768; off = 0; it = bb / 24; jt = bb % 24; R = 512; }
        const int i0 = it * 32, j0 = jt * 32;
        #pragma unroll
        for (int q = 0; q < 4; ++q)
            t[0][ty + 8 * q][tx] = src[(i0 + ty + 8 * q) * ld + off + j0 + tx];
        __syncthreads();
        #pragma unroll
        for (int q = 0; q < 4; ++q)
            dst[(j0 + ty + 8 * q) * R + i0 + tx] = t[0][tx][ty + 8 * q];
    } else {
        int bb = b - 672;
        const int mt = bb >> 3, jt = bb & 7;
        const int m0 = mt * 32, j0 = jt * 32;
        #pragma unroll
        for (int g = 0; g < 3; ++g)
            #pragma unroll
            for (int q = 0; q < 4; ++q)
                t[g][ty + 8 * q][tx] = Whh[(g * HM + j0 + ty + 8 * q) * HM + m0 + tx];
        __syncthreads();
        float4* dst = (float4*)(ws + WHHQ_OFF);
        #pragma unroll
        for (int q = 0; q < 4; ++q) {
            int ml = ty + 8 * q, jl = tx;
            dst[(size_t)(m0 + ml) * HM + j0 + jl] =
                make_float4(t[0][jl][ml], t[1][jl][ml], t[2][jl][ml], 0.0f);
        }
    }
}

// ---- gemm16: 16-row tiles, col-split; conflict-free broadcasts ----
// grid 512: [0,256) feat (rowb=bid>>1, colb=bid&1); [256,384) gates; [384,512) hterm
__global__ __launch_bounds__(256) void gemm16(
    const float* __restrict__ obs, const float* __restrict__ hmem,
    const float* __restrict__ b1,  const float* __restrict__ bc,
    const float* __restrict__ bhh, float* __restrict__ ws)
{
    __shared__ float s_act[16 * 512];   // 32 KB (feat); gates/hterm use 16*256
    const int tid = threadIdx.x;
    const int bid = blockIdx.x;

    if (bid < 256) {
        // ---- feat = relu(obs @ W1T + b1): 16 rows x 256 cols, K=512 ----
        const int m0 = (bid >> 1) * 16;
        const int c  = (bid & 1) * 256 + tid;       // global col
        for (int i = tid; i < 2048; i += 256) {
            int r = i >> 7, kq = i & 127;
            *(float4*)&s_act[r * 512 + kq * 4] =
                *(const float4*)&obs[(size_t)(m0 + r) * 512 + kq * 4];
        }
        __syncthreads();
        const float* __restrict__ Wt = ws + W1T_OFF;   // [512][512]
        float acc[16];
        #pragma unroll
        for (int r = 0; r < 16; ++r) acc[r] = 0.f;
        #pragma unroll 4
        for (int k4 = 0; k4 < 128; ++k4) {
            const int k = k4 * 4;
            float w0 = Wt[(k + 0) * 512 + c];
            float w1 = Wt[(k + 1) * 512 + c];
            float w2 = Wt[(k + 2) * 512 + c];
            float w3 = Wt[(k + 3) * 512 + c];
            #pragma unroll
            for (int r = 0; r < 16; ++r) {
                float4 o = *(const float4*)&s_act[r * 512 + k];  // uniform broadcast
                acc[r] = fmaf(o.x, w0, acc[r]); acc[r] = fmaf(o.y, w1, acc[r]);
                acc[r] = fmaf(o.z, w2, acc[r]); acc[r] = fmaf(o.w, w3, acc[r]);
            }
        }
        float bb = b1[c];
        float* F = ws + FEAT_OFF;
        #pragma unroll
        for (int r = 0; r < 16; ++r)
            F[(size_t)(m0 + r) * 512 + c] = fmaxf(acc[r] + bb, 0.f);
    } else if (bid < 384) {
        // ---- gates = h @ WhhT + b_hh: 16 rows x 256 j, K=256, gate-packed f4 ----
        const int m0 = (bid - 256) * 16;
        for (int i = tid; i < 1024; i += 256) {
            int r = i >> 6, kq = i & 63;
            *(float4*)&s_act[r * 256 + kq * 4] =
                *(const float4*)&hmem[(size_t)(m0 + r) * 256 + kq * 4];
        }
        __syncthreads();
        const float4* __restrict__ Q = (const float4*)(ws + WHHQ_OFF);  // [256][256]
        const int j = tid;
        float ar[16], az[16], an[16];
        #pragma unroll
        for (int r = 0; r < 16; ++r) { ar[r] = 0.f; az[r] = 0.f; an[r] = 0.f; }
        #pragma unroll 2
        for (int k4 = 0; k4 < 64; ++k4) {
            const int k = k4 * 4;
            float4 q0 = Q[(k + 0) * 256 + j];
            float4 q1 = Q[(k + 1) * 256 + j];
            float4 q2 = Q[(k + 2) * 256 + j];
            float4 q3 = Q[(k + 3) * 256 + j];
            #pragma unroll
            for (int r = 0; r < 16; ++r) {
                float4 h = *(const float4*)&s_act[r * 256 + k];  // uniform broadcast
                ar[r] = fmaf(h.x, q0.x, ar[r]); az[r] = fmaf(h.x, q0.y, az[r]); an[r] = fmaf(h.x, q0.z, an[r]);
                ar[r] = fmaf(h.y, q1.x, ar[r]); az[r] = fmaf(h.y, q1.y, az[r]); an[r] = fmaf(h.y, q1.z, an[r]);
                ar[r] = fmaf(h.z, q2.x, ar[r]); az[r] = fmaf(h.z, q2.y, az[r]); an[r] = fmaf(h.z, q2.z, an[r]);
                ar[r] = fmaf(h.w, q3.x, ar[r]); az[r] = fmaf(h.w, q3.y, az[r]); an[r] = fmaf(h.w, q3.z, an[r]);
            }
        }
        float br = bhh[j], bz = bhh[HM + j], bn = bhh[2 * HM + j];
        float* G = ws + GATES_OFF;
        #pragma unroll
        for (int r = 0; r < 16; ++r) {
            size_t base = (size_t)(m0 + r) * 768 + j;
            G[base]       = ar[r] + br;
            G[base + 256] = az[r] + bz;
            G[base + 512] = an[r] + bn;
        }
    } else {
        // ---- hterm = K2LE*(h @ WcT + bc): 16 rows x 128 cols, K=256 ----
        const int m0 = (bid - 384) * 16;
        for (int i = tid; i < 1024; i += 256) {
            int r = i >> 6, kq = i & 63;
            *(float4*)&s_act[r * 256 + kq * 4] =
                *(const float4*)&hmem[(size_t)(m0 + r) * 256 + kq * 4];
        }
        __syncthreads();
        const float* __restrict__ Wt = ws + WCT_OFF;   // [256][128]
        const int c  = tid & 127;
        const int r0 = (tid >> 7) * 8;                 // wave-uniform row half
        float acc[8];
        #pragma unroll
        for (int r = 0; r < 8; ++r) acc[r] = 0.f;
        #pragma unroll 4
        for (int k4 = 0; k4 < 64; ++k4) {
            const int k = k4 * 4;
            float w0 = Wt[(k + 0) * 128 + c];
            float w1 = Wt[(k + 1) * 128 + c];
            float w2 = Wt[(k + 2) * 128 + c];
            float w3 = Wt[(k + 3) * 128 + c];
            #pragma unroll
            for (int r = 0; r < 8; ++r) {
                float4 h = *(const float4*)&s_act[(r0 + r) * 256 + k];
                acc[r] = fmaf(h.x, w0, acc[r]); acc[r] = fmaf(h.y, w1, acc[r]);
                acc[r] = fmaf(h.z, w2, acc[r]); acc[r] = fmaf(h.w, w3, acc[r]);
            }
        }
        float bb = bc[c];
        float* H = ws + HTERM_OFF;
        #pragma unroll
        for (int r = 0; r < 8; ++r)
            H[(size_t)(m0 + r0 + r) * 128 + c] = K2LE * (acc[r] + bb);
    }
}

// ---- attention: tanh ctx + softmax + dset -> x; 4 rows/block, grid 512 ----
__global__ __launch_bounds__(512) void attn_kernel(
    const float* __restrict__ obs, const float* __restrict__ Wc,
    const float* __restrict__ Wa,  const float* __restrict__ ba,
    float* __restrict__ ws)
{
    __shared__ float s_obs[4][512];
    __shared__ float s_ht[4][128];
    __shared__ float s_alog[4][512];
    __shared__ float s_wc0[128], s_wa2[128];

    const int tid = threadIdx.x;
    const int row0 = blockIdx.x * 4;
    const float* hterm = ws + HTERM_OFF;
    float* X = ws + X_OFF;

    {
        int r = tid >> 7, kq = tid & 127;
        *(float4*)&s_obs[r][kq * 4] =
            *(const float4*)&obs[(size_t)(row0 + r) * 512 + kq * 4];
    }
    if (tid < 128) {
        int r = tid >> 5, kq = tid & 31;
        *(float4*)&s_ht[r][kq * 4] =
            *(const float4*)&hterm[(size_t)(row0 + r) * 128 + kq * 4];
    } else if (tid < 256) {
        int t = tid - 128;
        s_wc0[t] = K2LE * Wc[t * (HM + 1)];
        s_wa2[t] = 2.0f * Wa[t];
    }
    __syncthreads();

    {
        const float ba0 = ba[0];
        const int o = tid;
        float ob[4], acA[4];
        #pragma unroll
        for (int r = 0; r < 4; ++r) { ob[r] = s_obs[r][o]; acA[r] = 0.f; }
        float swa = 0.f;
        for (int c = 0; c < 128; c += 4) {
            float4 v = *(const float4*)&s_wa2[c];
            swa += v.x + v.y + v.z + v.w;
        }
        swa *= 0.5f;
        for (int c4 = 0; c4 < 32; ++c4) {
            float4 wc = *(const float4*)&s_wc0[c4 * 4];
            float4 wa = *(const float4*)&s_wa2[c4 * 4];
            #pragma unroll
            for (int r = 0; r < 4; ++r) {
                float4 ht = *(const float4*)&s_ht[r][c4 * 4];
                float t0 = fmaf(ob[r], wc.x, ht.x);
                acA[r] = fmaf(wa.x, RCPF(EXP2F(t0) + 1.f), acA[r]);
                float t1 = fmaf(ob[r], wc.y, ht.y);
                acA[r] = fmaf(wa.y, RCPF(EXP2F(t1) + 1.f), acA[r]);
                float t2 = fmaf(ob[r], wc.z, ht.z);
                acA[r] = fmaf(wa.z, RCPF(EXP2F(t2) + 1.f), acA[r]);
                float t3 = fmaf(ob[r], wc.w, ht.w);
                acA[r] = fmaf(wa.w, RCPF(EXP2F(t3) + 1.f), acA[r]);
            }
        }
        #pragma unroll
        for (int r = 0; r < 4; ++r) s_alog[r][o] = ba0 + swa - acA[r];
    }
    __syncthreads();

    {
        const int wv = tid >> 6, lane = tid & 63;
        if (wv < 4) {
            const int r = wv;
            float m = -1e30f;
            for (int o = lane; o < 512; o += 64) m = fmaxf(m, s_alog[r][o]);
            #pragma unroll
            for (int d = 32; d >= 1; d >>= 1) m = fmaxf(m, __shfl_xor(m, d));
            float se = 0.f, sw = 0.f;
            for (int o = lane; o < 512; o += 64) {
                float e = __expf(s_alog[r][o] - m);
                se += e; sw += e * s_obs[r][o];
            }
            #pragma unroll
            for (int d = 32; d >= 1; d >>= 1) { se += __shfl_xor(se, d); sw += __shfl_xor(sw, d); }
            if (lane == 0) X[row0 + r] = sw / se;
        }
    }
}

// ---- out2 GEMM: 16 rows x 128 cols/block; 4-way k-split x 2 col-groups ----
// grid 512: bid = rowb*4 + colb
__global__ __launch_bounds__(512) void out2_gemm(
    const float* __restrict__ hmem,  const float* __restrict__ W_ih,
    const float* __restrict__ b_ih,  const float* __restrict__ b2,
    float* __restrict__ ws)
{
    __shared__ float s_act[16 * 768];   // 48 KB; partials aliased in after GEMM
    const int tid = threadIdx.x;
    const int wv = tid >> 6, lane = tid & 63;
    const int rowb = blockIdx.x >> 2, colb = blockIdx.x & 3;
    const int m0 = rowb * 16;
    const float* F = ws + FEAT_OFF;
    const float* G = ws + GATES_OFF;
    const float* X = ws + X_OFF;

    // stage feat rows into [r][0..512)
    for (int i = tid; i < 2048; i += 512) {
        int r = i >> 7, kq = i & 127;
        *(float4*)&s_act[r * 768 + kq * 4] =
            *(const float4*)&F[(size_t)(m0 + r) * 512 + kq * 4];
    }
    // GRU finish -> [r][512..768)
    for (int i = tid; i < 4096; i += 512) {
        int r = i >> 8, j = i & 255;
        int grow = m0 + r;
        float g0 = G[(size_t)grow * 768 + j];
        float g1 = G[(size_t)grow * 768 + 256 + j];
        float g2 = G[(size_t)grow * 768 + 512 + j];
        float hp = hmem[(size_t)grow * 256 + j];
        float x  = X[grow];
        float rg = fast_sig(fmaf(x, W_ih[j], b_ih[j]) + g0);
        float zg = fast_sig(fmaf(x, W_ih[256 + j], b_ih[256 + j]) + g1);
        float ng = fast_tanh(fmaf(x, W_ih[512 + j], b_ih[512 + j]) + rg * g2);
        s_act[r * 768 + 512 + j] = (1.0f - zg) * ng + zg * hp;
    }
    __syncthreads();

    // 8 waves = (kg = wv&3: 192-k slice) x (cg = wv>>2: 64-col group)
    const float* __restrict__ Wt = ws + W2T_OFF;   // [768][512]
    const int kg = wv & 3, cg = wv >> 2;
    const int cl = cg * 64 + lane;          // local col [0,128)
    const int c  = colb * 128 + cl;         // global col [0,512)
    const int k0 = kg * 192;
    float acc[16];
    #pragma unroll
    for (int r = 0; r < 16; ++r) acc[r] = 0.f;
    #pragma unroll 4
    for (int k4 = 0; k4 < 48; ++k4) {
        const int k = k0 + k4 * 4;
        float w0 = Wt[(k + 0) * 512 + c];
        float w1 = Wt[(k + 1) * 512 + c];
        float w2 = Wt[(k + 2) * 512 + c];
        float w3 = Wt[(k + 3) * 512 + c];
        #pragma unroll
        for (int r = 0; r < 16; ++r) {
            float4 o = *(const float4*)&s_act[r * 768 + k];  // uniform broadcast
            acc[r] = fmaf(o.x, w0, acc[r]); acc[r] = fmaf(o.y, w1, acc[r]);
            acc[r] = fmaf(o.z, w2, acc[r]); acc[r] = fmaf(o.w, w3, acc[r]);
        }
    }
    __syncthreads();                    // all GEMM reads done; alias partials
    float* P = s_act;                   // [3][16][128]
    if (kg != 0) {
        #pragma unroll
        for (int r = 0; r < 16; ++r) P[((kg - 1) * 16 + r) * 128 + cl] = acc[r];
    }
    __syncthreads();
    if (kg == 0) {
        float bb = b2[c];
        float* O = ws + OUT2_OFF;
        #pragma unroll
        for (int r = 0; r < 16; ++r) {
            float v = acc[r] + P[(0 * 16 + r) * 128 + cl]
                             + P[(1 * 16 + r) * 128 + cl]
                             + P[(2 * 16 + r) * 128 + cl] + bb;
            O[(size_t)(m0 + r) * 512 + c] = fmaxf(v, 0.f);
        }
    }
}

// ---- heads + categorical sampling; wave per row, 8 rows/block ----
__global__ __launch_bounds__(512) void heads_kernel(
    const float* __restrict__ Wact,  const float* __restrict__ bact,
    const float* __restrict__ Wcrit, const float* __restrict__ bcrit,
    const float* __restrict__ ws,    float* __restrict__ out)
{
    const int wv = threadIdx.x >> 6, lane = threadIdx.x & 63;
    const int grow = blockIdx.x * 8 + wv;
    const float* o2 = ws + OUT2_OFF;

    float4 x0 = *(const float4*)&o2[(size_t)grow * 512 + lane * 8];
    float4 x1 = *(const float4*)&o2[(size_t)grow * 512 + lane * 8 + 4];

    float la[ACT];
    #pragma unroll
    for (int a = 0; a < ACT; ++a) {
        const float4* wa4 = (const float4*)&Wact[a * HS2 + lane * 8];
        float4 w0 = wa4[0], w1 = wa4[1];
        float p = x0.x * w0.x + x0.y * w0.y + x0.z * w0.z + x0.w * w0.w
                + x1.x * w1.x + x1.y * w1.y + x1.z * w1.z + x1.w * w1.w;
        #pragma unroll
        for (int d = 32; d >= 1; d >>= 1) p += __shfl_xor(p, d);
        la[a] = p + bact[a];
    }
    const float4* wc4 = (const float4*)&Wcrit[lane * 8];
    float4 w0 = wc4[0], w1 = wc4[1];
    float pv = x0.x * w0.x + x0.y * w0.y + x0.z * w0.z + x0.w * w0.w
             + x1.x * w1.x + x1.y * w1.y + x1.z * w1.z + x1.w * w1.w;
    #pragma unroll
    for (int d = 32; d >= 1; d >>= 1) pv += __shfl_xor(pv, d);

    float g = (lane < ACT) ? gumbel_ra(grow, lane) : 0.0f;
    float best = -1e30f; int amax = 0;
    float mx = -1e30f;
    #pragma unroll
    for (int a = 0; a < ACT; ++a) {
        float g_ = __shfl(g, a);
        float y = la[a] + g_;
        if (y > best) { best = y; amax = a; }   // first-max tie-break
        mx = fmaxf(mx, la[a]);
    }
    float se = 0.f;
    #pragma unroll
    for (int a = 0; a < ACT; ++a) se += __expf(la[a] - mx);
    float lse = mx + logf(se);
    float lp = la[amax] - lse;
    if (lane == 0) {
        out[grow]          = (float)amax;
        out[NW + grow]     = pv + bcrit[0];
        out[2 * NW + grow] = lp;
    }
}

extern "C" void kernel_launch(void* const* d_in, const int* in_sizes, int n_in,
                              void* d_out, int out_size, void* d_ws, size_t ws_size,
                              hipStream_t stream) {
    const float* obs   = (const float*)d_in[0];
    const float* hmem  = (const float*)d_in[1];
    const float* W1    = (const float*)d_in[2];
    const float* b1    = (const float*)d_in[3];
    const float* Wc    = (const float*)d_in[4];
    const float* bc    = (const float*)d_in[5];
    const float* Wa    = (const float*)d_in[6];
    const float* ba    = (const float*)d_in[7];
    const float* W_ih  = (const float*)d_in[8];
    const float* b_ih  = (const float*)d_in[9];
    const float* W_hh  = (const float*)d_in[10];
    const float* b_hh  = (const float*)d_in[11];
    const float* W2    = (const float*)d_in[12];
    const float* b2    = (const float*)d_in[13];
    const float* Wact  = (const float*)d_in[14];
    const float* bact  = (const float*)d_in[15];
    const float* Wcrit = (const float*)d_in[16];
    const float* bcrit = (const float*)d_in[17];
    float* ws = (float*)d_ws;

    transpose_weights<<<736, 256, 0, stream>>>(W1, Wc, W_hh, W2, ws);
    gemm16<<<512, 256, 0, stream>>>(obs, hmem, b1, bc, b_hh, ws);
    attn_kernel<<<512, 512, 0, stream>>>(obs, Wc, Wa, ba, ws);
    out2_gemm<<<512, 512, 0, stream>>>(hmem, W_ih, b_ih, b2, ws);
    heads_kernel<<<256, 512, 0, stream>>>(Wact, bact, Wcrit, bcrit, ws, (float*)d_out);
}

// Round 13
// 147.621 us; speedup vs baseline: 1.1834x; 1.1834x over previous
//
#include <hip/hip_runtime.h>
#include <stdint.h>

#define NW   2048
#define OBS  512
#define HS   512
#define HS2  512
#define HM   256
#define CTX  128
#define ACT  18

#define K2LE 2.8853900817779268f   // 2*log2(e)

// ws layout (floats)
#define W1T_OFF   0          // [512 k][512 c]
#define WCT_OFF   262144     // [256 m][128 c]
#define W2T_OFF   294912     // [768 k][512 c]
#define WHHQ_OFF  688128     // [256 m][256 j] float4 (Wr,Wz,Wn,0)
#define FEAT_OFF  950272     // [2048][512]
#define GATES_OFF 1998848    // [2048][768]  (b_hh added)
#define HTERM_OFF 3571712    // [2048][128]  (K2LE-prescaled, bc added)
#define X_OFF     3833856    // [2048]
#define OUT2_OFF  3835904    // [2048][512]
// total 4,884,480 floats = 19.5 MB

#if __has_builtin(__builtin_amdgcn_exp2f)
#define EXP2F(x) __builtin_amdgcn_exp2f(x)
#else
#define EXP2F(x) exp2f(x)
#endif
#if __has_builtin(__builtin_amdgcn_rcpf)
#define RCPF(x) __builtin_amdgcn_rcpf(x)
#else
#define RCPF(x) (1.0f/(x))
#endif

// ---------------- threefry2x32 (key = (0,42)), 20 rounds ----------------
#define TFR(x0, x1, R) { x0 += x1; x1 = (x1 << R) | (x1 >> (32 - R)); x1 ^= x0; }

__device__ __forceinline__ void threefry_0_42(uint32_t x0, uint32_t x1,
                                              uint32_t& o0, uint32_t& o1) {
    const uint32_t ks0 = 0u;
    const uint32_t ks1 = 42u;
    const uint32_t ks2 = 0x1BD11BDAu ^ ks0 ^ ks1;
    x0 += ks0; x1 += ks1;
    TFR(x0, x1, 13) TFR(x0, x1, 15) TFR(x0, x1, 26) TFR(x0, x1, 6)
    x0 += ks1; x1 += ks2 + 1u;
    TFR(x0, x1, 17) TFR(x0, x1, 29) TFR(x0, x1, 16) TFR(x0, x1, 24)
    x0 += ks2; x1 += ks0 + 2u;
    TFR(x0, x1, 13) TFR(x0, x1, 15) TFR(x0, x1, 26) TFR(x0, x1, 6)
    x0 += ks0; x1 += ks1 + 3u;
    TFR(x0, x1, 17) TFR(x0, x1, 29) TFR(x0, x1, 16) TFR(x0, x1, 24)
    x0 += ks1; x1 += ks2 + 4u;
    TFR(x0, x1, 13) TFR(x0, x1, 15) TFR(x0, x1, 26) TFR(x0, x1, 6)
    x0 += ks2; x1 += ks0 + 5u;
    o0 = x0; o1 = x1;
}

// jax_threefry_partitionable scheme (verified round 2): counter=(0,n), out0^out1
__device__ __forceinline__ float gumbel_ra(int row, int a) {
    uint32_t n = (uint32_t)(row * ACT + a);
    uint32_t o0, o1;
    threefry_0_42(0u, n, o0, o1);
    uint32_t bits = o0 ^ o1;
    uint32_t fb = (bits >> 9) | 0x3F800000u;
    float f = __uint_as_float(fb) - 1.0f;
    const float tiny = 1.17549435e-38f;
    float u = (f < tiny) ? tiny : f;
    return -logf(-logf(u));
}

__device__ __forceinline__ float fast_tanh(float x) {
    float e = __expf(2.0f * x);
    return 1.0f - 2.0f / (e + 1.0f);
}
__device__ __forceinline__ float fast_sig(float x) {
    return 1.0f / (1.0f + __expf(-x));
}

// ---- weight prep: transposes + GRU gate-pack into ws ----
__global__ __launch_bounds__(256) void transpose_weights(
    const float* __restrict__ W1, const float* __restrict__ Wc,
    const float* __restrict__ Whh, const float* __restrict__ W2,
    float* __restrict__ ws)
{
    __shared__ float t[3][32][33];
    const int tx = threadIdx.x & 31, ty = threadIdx.x >> 5;   // 32 x 8
    int b = blockIdx.x;
    if (b < 672) {
        const float* src; float* dst; int ld, off, R, it, jt;
        if (b < 256)      { src = W1;  dst = ws + W1T_OFF;  ld = 512; off = 0; it = b >> 4; jt = b & 15; R = 512; }
        else if (b < 288) { int bb = b - 256; src = Wc;  dst = ws + WCT_OFF;  ld = 257; off = 1; it = bb >> 3; jt = bb & 7;  R = 128; }
        else              { int bb = b - 288; src = W2;  dst = ws + W2T_OFF;  ld = 768; off = 0; it = bb / 24; jt = bb % 24; R = 512; }
        const int i0 = it * 32, j0 = jt * 32;
        #pragma unroll
        for (int q = 0; q < 4; ++q)
            t[0][ty + 8 * q][tx] = src[(i0 + ty + 8 * q) * ld + off + j0 + tx];
        __syncthreads();
        #pragma unroll
        for (int q = 0; q < 4; ++q)
            dst[(j0 + ty + 8 * q) * R + i0 + tx] = t[0][tx][ty + 8 * q];
    } else {
        int bb = b - 672;
        const int mt = bb >> 3, jt = bb & 7;
        const int m0 = mt * 32, j0 = jt * 32;
        #pragma unroll
        for (int g = 0; g < 3; ++g)
            #pragma unroll
            for (int q = 0; q < 4; ++q)
                t[g][ty + 8 * q][tx] = Whh[(g * HM + j0 + ty + 8 * q) * HM + m0 + tx];
        __syncthreads();
        float4* dst = (float4*)(ws + WHHQ_OFF);
        #pragma unroll
        for (int q = 0; q < 4; ++q) {
            int ml = ty + 8 * q, jl = tx;
            dst[(size_t)(m0 + ml) * HM + j0 + jl] =
                make_float4(t[0][jl][ml], t[1][jl][ml], t[2][jl][ml], 0.0f);
        }
    }
}

// ---- gemm16: 16-row tiles, f2/f4 vector weight loads, cross-wave k-split ----
// grid 512: [0,256) feat (rowb=bid>>1, colb=bid&1); [256,384) gates; [384,512) hterm
__global__ __launch_bounds__(256) void gemm16(
    const float* __restrict__ obs, const float* __restrict__ hmem,
    const float* __restrict__ b1,  const float* __restrict__ bc,
    const float* __restrict__ bhh, float* __restrict__ ws)
{
    __shared__ float s_act[16 * 512];   // 32 KB (feat); partials aliased after sync
    const int tid = threadIdx.x;
    const int bid = blockIdx.x;

    if (bid < 256) {
        // ---- feat = relu(obs @ W1T + b1): 16 rows x 256 cols (f2), 2-way kg ----
        const int m0 = (bid >> 1) * 16;
        const int colb = bid & 1;
        for (int i = tid; i < 2048; i += 256) {
            int r = i >> 7, kq = i & 127;
            *(float4*)&s_act[r * 512 + kq * 4] =
                *(const float4*)&obs[(size_t)(m0 + r) * 512 + kq * 4];
        }
        __syncthreads();
        const float2* __restrict__ Wt = (const float2*)(ws + W1T_OFF);  // [512][256 f2]
        const int c2l = tid & 127;
        const int kg  = tid >> 7;             // 0/1, wave-uniform
        const int c2g = colb * 128 + c2l;
        const int k0  = kg * 256;
        float2 acc[16];
        #pragma unroll
        for (int r = 0; r < 16; ++r) acc[r] = make_float2(0.f, 0.f);
        #pragma unroll 4
        for (int k4 = 0; k4 < 64; ++k4) {
            const int k = k0 + k4 * 4;
            float2 w0 = Wt[(k + 0) * 256 + c2g];
            float2 w1 = Wt[(k + 1) * 256 + c2g];
            float2 w2 = Wt[(k + 2) * 256 + c2g];
            float2 w3 = Wt[(k + 3) * 256 + c2g];
            #pragma unroll
            for (int r = 0; r < 16; ++r) {
                float4 o = *(const float4*)&s_act[r * 512 + k];  // uniform broadcast
                acc[r].x = fmaf(o.x, w0.x, acc[r].x); acc[r].y = fmaf(o.x, w0.y, acc[r].y);
                acc[r].x = fmaf(o.y, w1.x, acc[r].x); acc[r].y = fmaf(o.y, w1.y, acc[r].y);
                acc[r].x = fmaf(o.z, w2.x, acc[r].x); acc[r].y = fmaf(o.z, w2.y, acc[r].y);
                acc[r].x = fmaf(o.w, w3.x, acc[r].x); acc[r].y = fmaf(o.w, w3.y, acc[r].y);
            }
        }
        __syncthreads();                 // staging reads done; alias partials
        float2* P2 = (float2*)s_act;     // [16][128] f2 = 16 KB
        if (kg == 1) {
            #pragma unroll
            for (int r = 0; r < 16; ++r) P2[r * 128 + c2l] = acc[r];
        }
        __syncthreads();
        if (kg == 0) {
            float2 bb = ((const float2*)b1)[c2g];
            float* F = ws + FEAT_OFF;
            #pragma unroll
            for (int r = 0; r < 16; ++r) {
                float2 p = P2[r * 128 + c2l];
                float2 v;
                v.x = fmaxf(acc[r].x + p.x + bb.x, 0.f);
                v.y = fmaxf(acc[r].y + p.y + bb.y, 0.f);
                *(float2*)&F[(size_t)(m0 + r) * 512 + c2g * 2] = v;
            }
        }
    } else if (bid < 384) {
        // ---- gates = h @ WhhT + b_hh: 16 rows x 256 j, K=256, gate-packed f4 ----
        const int m0 = (bid - 256) * 16;
        for (int i = tid; i < 1024; i += 256) {
            int r = i >> 6, kq = i & 63;
            *(float4*)&s_act[r * 256 + kq * 4] =
                *(const float4*)&hmem[(size_t)(m0 + r) * 256 + kq * 4];
        }
        __syncthreads();
        const float4* __restrict__ Q = (const float4*)(ws + WHHQ_OFF);  // [256][256]
        const int j = tid;
        float ar[16], az[16], an[16];
        #pragma unroll
        for (int r = 0; r < 16; ++r) { ar[r] = 0.f; az[r] = 0.f; an[r] = 0.f; }
        #pragma unroll 2
        for (int k4 = 0; k4 < 64; ++k4) {
            const int k = k4 * 4;
            float4 q0 = Q[(k + 0) * 256 + j];
            float4 q1 = Q[(k + 1) * 256 + j];
            float4 q2 = Q[(k + 2) * 256 + j];
            float4 q3 = Q[(k + 3) * 256 + j];
            #pragma unroll
            for (int r = 0; r < 16; ++r) {
                float4 h = *(const float4*)&s_act[r * 256 + k];  // uniform broadcast
                ar[r] = fmaf(h.x, q0.x, ar[r]); az[r] = fmaf(h.x, q0.y, az[r]); an[r] = fmaf(h.x, q0.z, an[r]);
                ar[r] = fmaf(h.y, q1.x, ar[r]); az[r] = fmaf(h.y, q1.y, az[r]); an[r] = fmaf(h.y, q1.z, an[r]);
                ar[r] = fmaf(h.z, q2.x, ar[r]); az[r] = fmaf(h.z, q2.y, az[r]); an[r] = fmaf(h.z, q2.z, an[r]);
                ar[r] = fmaf(h.w, q3.x, ar[r]); az[r] = fmaf(h.w, q3.y, az[r]); an[r] = fmaf(h.w, q3.z, an[r]);
            }
        }
        float br = bhh[j], bz = bhh[HM + j], bn = bhh[2 * HM + j];
        float* G = ws + GATES_OFF;
        #pragma unroll
        for (int r = 0; r < 16; ++r) {
            size_t base = (size_t)(m0 + r) * 768 + j;
            G[base]       = ar[r] + br;
            G[base + 256] = az[r] + bz;
            G[base + 512] = an[r] + bn;
        }
    } else {
        // ---- hterm = K2LE*(h @ WcT + bc): 16 rows x 128 cols, K=256 ----
        const int m0 = (bid - 384) * 16;
        for (int i = tid; i < 1024; i += 256) {
            int r = i >> 6, kq = i & 63;
            *(float4*)&s_act[r * 256 + kq * 4] =
                *(const float4*)&hmem[(size_t)(m0 + r) * 256 + kq * 4];
        }
        __syncthreads();
        const float* __restrict__ Wt = ws + WCT_OFF;   // [256][128]
        const int c  = tid & 127;
        const int r0 = (tid >> 7) * 8;                 // wave-uniform row half
        float acc[8];
        #pragma unroll
        for (int r = 0; r < 8; ++r) acc[r] = 0.f;
        #pragma unroll 4
        for (int k4 = 0; k4 < 64; ++k4) {
            const int k = k4 * 4;
            float w0 = Wt[(k + 0) * 128 + c];
            float w1 = Wt[(k + 1) * 128 + c];
            float w2 = Wt[(k + 2) * 128 + c];
            float w3 = Wt[(k + 3) * 128 + c];
            #pragma unroll
            for (int r = 0; r < 8; ++r) {
                float4 h = *(const float4*)&s_act[(r0 + r) * 256 + k];
                acc[r] = fmaf(h.x, w0, acc[r]); acc[r] = fmaf(h.y, w1, acc[r]);
                acc[r] = fmaf(h.z, w2, acc[r]); acc[r] = fmaf(h.w, w3, acc[r]);
            }
        }
        float bb = bc[c];
        float* H = ws + HTERM_OFF;
        #pragma unroll
        for (int r = 0; r < 8; ++r)
            H[(size_t)(m0 + r0 + r) * 128 + c] = K2LE * (acc[r] + bb);
    }
}

// ---- attention: tanh ctx + softmax + dset -> x; 4 rows/block, grid 512 ----
__global__ __launch_bounds__(512) void attn_kernel(
    const float* __restrict__ obs, const float* __restrict__ Wc,
    const float* __restrict__ Wa,  const float* __restrict__ ba,
    float* __restrict__ ws)
{
    __shared__ float s_obs[4][512];
    __shared__ float s_ht[4][128];
    __shared__ float s_alog[4][512];
    __shared__ float s_wc0[128], s_wa2[128];

    const int tid = threadIdx.x;
    const int row0 = blockIdx.x * 4;
    const float* hterm = ws + HTERM_OFF;
    float* X = ws + X_OFF;

    {
        int r = tid >> 7, kq = tid & 127;
        *(float4*)&s_obs[r][kq * 4] =
            *(const float4*)&obs[(size_t)(row0 + r) * 512 + kq * 4];
    }
    if (tid < 128) {
        int r = tid >> 5, kq = tid & 31;
        *(float4*)&s_ht[r][kq * 4] =
            *(const float4*)&hterm[(size_t)(row0 + r) * 128 + kq * 4];
    } else if (tid < 256) {
        int t = tid - 128;
        s_wc0[t] = K2LE * Wc[t * (HM + 1)];
        s_wa2[t] = 2.0f * Wa[t];
    }
    __syncthreads();

    {
        const float ba0 = ba[0];
        const int o = tid;
        float ob[4], acA[4];
        #pragma unroll
        for (int r = 0; r < 4; ++r) { ob[r] = s_obs[r][o]; acA[r] = 0.f; }
        float swa = 0.f;
        for (int c = 0; c < 128; c += 4) {
            float4 v = *(const float4*)&s_wa2[c];
            swa += v.x + v.y + v.z + v.w;
        }
        swa *= 0.5f;
        for (int c4 = 0; c4 < 32; ++c4) {
            float4 wc = *(const float4*)&s_wc0[c4 * 4];
            float4 wa = *(const float4*)&s_wa2[c4 * 4];
            #pragma unroll
            for (int r = 0; r < 4; ++r) {
                float4 ht = *(const float4*)&s_ht[r][c4 * 4];
                float t0 = fmaf(ob[r], wc.x, ht.x);
                acA[r] = fmaf(wa.x, RCPF(EXP2F(t0) + 1.f), acA[r]);
                float t1 = fmaf(ob[r], wc.y, ht.y);
                acA[r] = fmaf(wa.y, RCPF(EXP2F(t1) + 1.f), acA[r]);
                float t2 = fmaf(ob[r], wc.z, ht.z);
                acA[r] = fmaf(wa.z, RCPF(EXP2F(t2) + 1.f), acA[r]);
                float t3 = fmaf(ob[r], wc.w, ht.w);
                acA[r] = fmaf(wa.w, RCPF(EXP2F(t3) + 1.f), acA[r]);
            }
        }
        #pragma unroll
        for (int r = 0; r < 4; ++r) s_alog[r][o] = ba0 + swa - acA[r];
    }
    __syncthreads();

    {
        const int wv = tid >> 6, lane = tid & 63;
        if (wv < 4) {
            const int r = wv;
            float m = -1e30f;
            for (int o = lane; o < 512; o += 64) m = fmaxf(m, s_alog[r][o]);
            #pragma unroll
            for (int d = 32; d >= 1; d >>= 1) m = fmaxf(m, __shfl_xor(m, d));
            float se = 0.f, sw = 0.f;
            for (int o = lane; o < 512; o += 64) {
                float e = __expf(s_alog[r][o] - m);
                se += e; sw += e * s_obs[r][o];
            }
            #pragma unroll
            for (int d = 32; d >= 1; d >>= 1) { se += __shfl_xor(se, d); sw += __shfl_xor(sw, d); }
            if (lane == 0) X[row0 + r] = sw / se;
        }
    }
}

// ---- out2 GEMM: 16 rows x 128 cols (f2), 4-way cross-wave k-split, col-split x4 ----
// grid 512: bid = rowb*4 + colb; 256 threads
__global__ __launch_bounds__(256) void out2_gemm(
    const float* __restrict__ hmem,  const float* __restrict__ W_ih,
    const float* __restrict__ b_ih,  const float* __restrict__ b2,
    float* __restrict__ ws)
{
    __shared__ float s_act[16 * 768];   // 48 KB; partials aliased after GEMM
    const int tid = threadIdx.x;
    const int rowb = blockIdx.x >> 2, colb = blockIdx.x & 3;
    const int m0 = rowb * 16;
    const float* F = ws + FEAT_OFF;
    const float* G = ws + GATES_OFF;
    const float* X = ws + X_OFF;

    // stage feat rows into [r][0..512)
    for (int i = tid; i < 2048; i += 256) {
        int r = i >> 7, kq = i & 127;
        *(float4*)&s_act[r * 768 + kq * 4] =
            *(const float4*)&F[(size_t)(m0 + r) * 512 + kq * 4];
    }
    // GRU finish -> [r][512..768)
    for (int i = tid; i < 4096; i += 256) {
        int r = i >> 8, j = i & 255;
        int grow = m0 + r;
        float g0 = G[(size_t)grow * 768 + j];
        float g1 = G[(size_t)grow * 768 + 256 + j];
        float g2 = G[(size_t)grow * 768 + 512 + j];
        float hp = hmem[(size_t)grow * 256 + j];
        float x  = X[grow];
        float rg = fast_sig(fmaf(x, W_ih[j], b_ih[j]) + g0);
        float zg = fast_sig(fmaf(x, W_ih[256 + j], b_ih[256 + j]) + g1);
        float ng = fast_tanh(fmaf(x, W_ih[512 + j], b_ih[512 + j]) + rg * g2);
        s_act[r * 768 + 512 + j] = (1.0f - zg) * ng + zg * hp;
    }
    __syncthreads();

    // 4 waves = 4 kg k-slices (192 each); lane owns f2 col within 64-f2 group
    const float2* __restrict__ Wt = (const float2*)(ws + W2T_OFF);  // [768][256 f2]
    const int c2l = tid & 63;
    const int kg  = tid >> 6;            // 0..3, wave-uniform
    const int c2g = colb * 64 + c2l;     // global f2 col [0,256)
    const int k0  = kg * 192;
    float2 acc[16];
    #pragma unroll
    for (int r = 0; r < 16; ++r) acc[r] = make_float2(0.f, 0.f);
    #pragma unroll 4
    for (int k4 = 0; k4 < 48; ++k4) {
        const int k = k0 + k4 * 4;
        float2 w0 = Wt[(k + 0) * 256 + c2g];
        float2 w1 = Wt[(k + 1) * 256 + c2g];
        float2 w2 = Wt[(k + 2) * 256 + c2g];
        float2 w3 = Wt[(k + 3) * 256 + c2g];
        #pragma unroll
        for (int r = 0; r < 16; ++r) {
            float4 o = *(const float4*)&s_act[r * 768 + k];  // uniform broadcast
            acc[r].x = fmaf(o.x, w0.x, acc[r].x); acc[r].y = fmaf(o.x, w0.y, acc[r].y);
            acc[r].x = fmaf(o.y, w1.x, acc[r].x); acc[r].y = fmaf(o.y, w1.y, acc[r].y);
            acc[r].x = fmaf(o.z, w2.x, acc[r].x); acc[r].y = fmaf(o.z, w2.y, acc[r].y);
            acc[r].x = fmaf(o.w, w3.x, acc[r].x); acc[r].y = fmaf(o.w, w3.y, acc[r].y);
        }
    }
    __syncthreads();                    // all GEMM reads done; alias partials
    float2* P2 = (float2*)s_act;        // [3][16][64] f2 = 12 KB
    if (kg != 0) {
        #pragma unroll
        for (int r = 0; r < 16; ++r) P2[((kg - 1) * 16 + r) * 64 + c2l] = acc[r];
    }
    __syncthreads();
    if (kg == 0) {
        float2 bb = ((const float2*)b2)[c2g];
        float* O = ws + OUT2_OFF;
        #pragma unroll
        for (int r = 0; r < 16; ++r) {
            float2 p0 = P2[(0 * 16 + r) * 64 + c2l];
            float2 p1 = P2[(1 * 16 + r) * 64 + c2l];
            float2 p2 = P2[(2 * 16 + r) * 64 + c2l];
            float2 v;
            v.x = fmaxf(acc[r].x + p0.x + p1.x + p2.x + bb.x, 0.f);
            v.y = fmaxf(acc[r].y + p0.y + p1.y + p2.y + bb.y, 0.f);
            *(float2*)&O[(size_t)(m0 + r) * 512 + c2g * 2] = v;
        }
    }
}

// ---- heads + categorical sampling; wave per row, 8 rows/block ----
__global__ __launch_bounds__(512) void heads_kernel(
    const float* __restrict__ Wact,  const float* __restrict__ bact,
    const float* __restrict__ Wcrit, const float* __restrict__ bcrit,
    const float* __restrict__ ws,    float* __restrict__ out)
{
    const int wv = threadIdx.x >> 6, lane = threadIdx.x & 63;
    const int grow = blockIdx.x * 8 + wv;
    const float* o2 = ws + OUT2_OFF;

    float4 x0 = *(const float4*)&o2[(size_t)grow * 512 + lane * 8];
    float4 x1 = *(const float4*)&o2[(size_t)grow * 512 + lane * 8 + 4];

    float la[ACT];
    #pragma unroll
    for (int a = 0; a < ACT; ++a) {
        const float4* wa4 = (const float4*)&Wact[a * HS2 + lane * 8];
        float4 w0 = wa4[0], w1 = wa4[1];
        float p = x0.x * w0.x + x0.y * w0.y + x0.z * w0.z + x0.w * w0.w
                + x1.x * w1.x + x1.y * w1.y + x1.z * w1.z + x1.w * w1.w;
        #pragma unroll
        for (int d = 32; d >= 1; d >>= 1) p += __shfl_xor(p, d);
        la[a] = p + bact[a];
    }
    const float4* wc4 = (const float4*)&Wcrit[lane * 8];
    float4 w0 = wc4[0], w1 = wc4[1];
    float pv = x0.x * w0.x + x0.y * w0.y + x0.z * w0.z + x0.w * w0.w
             + x1.x * w1.x + x1.y * w1.y + x1.z * w1.z + x1.w * w1.w;
    #pragma unroll
    for (int d = 32; d >= 1; d >>= 1) pv += __shfl_xor(pv, d);

    float g = (lane < ACT) ? gumbel_ra(grow, lane) : 0.0f;
    float best = -1e30f; int amax = 0;
    float mx = -1e30f;
    #pragma unroll
    for (int a = 0; a < ACT; ++a) {
        float g_ = __shfl(g, a);
        float y = la[a] + g_;
        if (y > best) { best = y; amax = a; }   // first-max tie-break
        mx = fmaxf(mx, la[a]);
    }
    float se = 0.f;
    #pragma unroll
    for (int a = 0; a < ACT; ++a) se += __expf(la[a] - mx);
    float lse = mx + logf(se);
    float lp = la[amax] - lse;
    if (lane == 0) {
        out[grow]          = (float)amax;
        out[NW + grow]     = pv + bcrit[0];
        out[2 * NW + grow] = lp;
    }
}

extern "C" void kernel_launch(void* const* d_in, const int* in_sizes, int n_in,
                              void* d_out, int out_size, void* d_ws, size_t ws_size,
                              hipStream_t stream) {
    const float* obs   = (const float*)d_in[0];
    const float* hmem  = (const float*)d_in[1];
    const float* W1    = (const float*)d_in[2];
    const float* b1    = (const float*)d_in[3];
    const float* Wc    = (const float*)d_in[4];
    const float* bc    = (const float*)d_in[5];
    const float* Wa    = (const float*)d_in[6];
    const float* ba    = (const float*)d_in[7];
    const float* W_ih  = (const float*)d_in[8];
    const float* b_ih  = (const float*)d_in[9];
    const float* W_hh  = (const float*)d_in[10];
    const float* b_hh  = (const float*)d_in[11];
    const float* W2    = (const float*)d_in[12];
    const float* b2    = (const float*)d_in[13];
    const float* Wact  = (const float*)d_in[14];
    const float* bact  = (const float*)d_in[15];
    const float* Wcrit = (const float*)d_in[16];
    const float* bcrit = (const float*)d_in[17];
    float* ws = (float*)d_ws;

    transpose_weights<<<736, 256, 0, stream>>>(W1, Wc, W_hh, W2, ws);
    gemm16<<<512, 256, 0, stream>>>(obs, hmem, b1, bc, b_hh, ws);
    attn_kernel<<<512, 512, 0, stream>>>(obs, Wc, Wa, ba, ws);
    out2_gemm<<<512, 256, 0, stream>>>(hmem, W_ih, b_ih, b2, ws);
    heads_kernel<<<256, 512, 0, stream>>>(Wact, bact, Wcrit, bcrit, ws, (float*)d_out);
}

// Round 14
// 117.902 us; speedup vs baseline: 1.4817x; 1.2521x over previous
//
#include <hip/hip_runtime.h>
#include <stdint.h>

#define NW   2048
#define OBS  512
#define HS   512
#define HS2  512
#define HM   256
#define CTX  128
#define ACT  18

#define K2LE 2.8853900817779268f   // 2*log2(e)

// ws layout (floats)
#define W1T_OFF   0          // [512 k][512 c]
#define WCT_OFF   262144     // [256 m][128 c]
#define W2T_OFF   294912     // [768 k][512 c]
#define WHHQ_OFF  688128     // [256 m][256 j] float4 (Wr,Wz,Wn,0)
#define FEAT_OFF  950272     // [2048][512]
#define GATES_OFF 1998848    // [2048][768]  (b_hh added)
#define HTERM_OFF 3571712    // [2048][128]  (K2LE-prescaled, bc added)
#define X_OFF     3833856    // [2048]
#define OUT2_OFF  3835904    // [2048][512]
// total 4,884,480 floats = 19.5 MB

#if __has_builtin(__builtin_amdgcn_exp2f)
#define EXP2F(x) __builtin_amdgcn_exp2f(x)
#else
#define EXP2F(x) exp2f(x)
#endif
#if __has_builtin(__builtin_amdgcn_rcpf)
#define RCPF(x) __builtin_amdgcn_rcpf(x)
#else
#define RCPF(x) (1.0f/(x))
#endif

// ---------------- threefry2x32 (key = (0,42)), 20 rounds ----------------
#define TFR(x0, x1, R) { x0 += x1; x1 = (x1 << R) | (x1 >> (32 - R)); x1 ^= x0; }

__device__ __forceinline__ void threefry_0_42(uint32_t x0, uint32_t x1,
                                              uint32_t& o0, uint32_t& o1) {
    const uint32_t ks0 = 0u;
    const uint32_t ks1 = 42u;
    const uint32_t ks2 = 0x1BD11BDAu ^ ks0 ^ ks1;
    x0 += ks0; x1 += ks1;
    TFR(x0, x1, 13) TFR(x0, x1, 15) TFR(x0, x1, 26) TFR(x0, x1, 6)
    x0 += ks1; x1 += ks2 + 1u;
    TFR(x0, x1, 17) TFR(x0, x1, 29) TFR(x0, x1, 16) TFR(x0, x1, 24)
    x0 += ks2; x1 += ks0 + 2u;
    TFR(x0, x1, 13) TFR(x0, x1, 15) TFR(x0, x1, 26) TFR(x0, x1, 6)
    x0 += ks0; x1 += ks1 + 3u;
    TFR(x0, x1, 17) TFR(x0, x1, 29) TFR(x0, x1, 16) TFR(x0, x1, 24)
    x0 += ks1; x1 += ks2 + 4u;
    TFR(x0, x1, 13) TFR(x0, x1, 15) TFR(x0, x1, 26) TFR(x0, x1, 6)
    x0 += ks2; x1 += ks0 + 5u;
    o0 = x0; o1 = x1;
}

// jax_threefry_partitionable scheme (verified round 2): counter=(0,n), out0^out1
__device__ __forceinline__ float gumbel_ra(int row, int a) {
    uint32_t n = (uint32_t)(row * ACT + a);
    uint32_t o0, o1;
    threefry_0_42(0u, n, o0, o1);
    uint32_t bits = o0 ^ o1;
    uint32_t fb = (bits >> 9) | 0x3F800000u;
    float f = __uint_as_float(fb) - 1.0f;
    const float tiny = 1.17549435e-38f;
    float u = (f < tiny) ? tiny : f;
    return -logf(-logf(u));
}

__device__ __forceinline__ float fast_tanh(float x) {
    float e = __expf(2.0f * x);
    return 1.0f - 2.0f / (e + 1.0f);
}
__device__ __forceinline__ float fast_sig(float x) {
    return 1.0f / (1.0f + __expf(-x));
}

// ---- weight prep: transposes + GRU gate-pack into ws ----
__global__ __launch_bounds__(256) void transpose_weights(
    const float* __restrict__ W1, const float* __restrict__ Wc,
    const float* __restrict__ Whh, const float* __restrict__ W2,
    float* __restrict__ ws)
{
    __shared__ float t[3][32][33];
    const int tx = threadIdx.x & 31, ty = threadIdx.x >> 5;   // 32 x 8
    int b = blockIdx.x;
    if (b < 672) {
        const float* src; float* dst; int ld, off, R, it, jt;
        if (b < 256)      { src = W1;  dst = ws + W1T_OFF;  ld = 512; off = 0; it = b >> 4; jt = b & 15; R = 512; }
        else if (b < 288) { int bb = b - 256; src = Wc;  dst = ws + WCT_OFF;  ld = 257; off = 1; it = bb >> 3; jt = bb & 7;  R = 128; }
        else              { int bb = b - 288; src = W2;  dst = ws + W2T_OFF;  ld = 768; off = 0; it = bb / 24; jt = bb % 24; R = 512; }
        const int i0 = it * 32, j0 = jt * 32;
        #pragma unroll
        for (int q = 0; q < 4; ++q)
            t[0][ty + 8 * q][tx] = src[(i0 + ty + 8 * q) * ld + off + j0 + tx];
        __syncthreads();
        #pragma unroll
        for (int q = 0; q < 4; ++q)
            dst[(j0 + ty + 8 * q) * R + i0 + tx] = t[0][tx][ty + 8 * q];
    } else {
        int bb = b - 672;
        const int mt = bb >> 3, jt = bb & 7;
        const int m0 = mt * 32, j0 = jt * 32;
        #pragma unroll
        for (int g = 0; g < 3; ++g)
            #pragma unroll
            for (int q = 0; q < 4; ++q)
                t[g][ty + 8 * q][tx] = Whh[(g * HM + j0 + ty + 8 * q) * HM + m0 + tx];
        __syncthreads();
        float4* dst = (float4*)(ws + WHHQ_OFF);
        #pragma unroll
        for (int q = 0; q < 4; ++q) {
            int ml = ty + 8 * q, jl = tx;
            dst[(size_t)(m0 + ml) * HM + j0 + jl] =
                make_float4(t[0][jl][ml], t[1][jl][ml], t[2][jl][ml], 0.0f);
        }
    }
}

// ---- gemm8v2: 8-row tiles, col-split grids, 2-way cross-wave k-split ----
// grid 1280: [0,512) feat (rowb=bid>>1, colb=bid&1);
//            [512,1024) gates (rowb=(bid-512)>>1, jb=bid&1);
//            [1024,1280) hterm
__global__ __launch_bounds__(256) void gemm8v2(
    const float* __restrict__ obs, const float* __restrict__ hmem,
    const float* __restrict__ b1,  const float* __restrict__ bc,
    const float* __restrict__ bhh, float* __restrict__ ws)
{
    __shared__ float s_act[8 * 512];   // 16 KB; partials aliased after k-loop
    const int tid = threadIdx.x;
    const int bid = blockIdx.x;

    if (bid < 512) {
        // ---- feat = relu(obs @ W1T + b1): 8 rows x 256 cols (f2), 2-way kg ----
        const int m0 = (bid >> 1) * 8;
        const int colb = bid & 1;
        for (int i = tid; i < 1024; i += 256) {
            int r = i >> 7, kq = i & 127;
            *(float4*)&s_act[r * 512 + kq * 4] =
                *(const float4*)&obs[(size_t)(m0 + r) * 512 + kq * 4];
        }
        __syncthreads();
        const float2* __restrict__ Wt = (const float2*)(ws + W1T_OFF);  // [512][256 f2]
        const int c2l = tid & 127;
        const int kg  = tid >> 7;             // 0/1, wave-uniform
        const int c2g = colb * 128 + c2l;
        const int k0  = kg * 256;
        float2 acc[8];
        #pragma unroll
        for (int r = 0; r < 8; ++r) acc[r] = make_float2(0.f, 0.f);
        #pragma unroll 4
        for (int k4 = 0; k4 < 64; ++k4) {
            const int k = k0 + k4 * 4;
            float2 w0 = Wt[(k + 0) * 256 + c2g];
            float2 w1 = Wt[(k + 1) * 256 + c2g];
            float2 w2 = Wt[(k + 2) * 256 + c2g];
            float2 w3 = Wt[(k + 3) * 256 + c2g];
            #pragma unroll
            for (int r = 0; r < 8; ++r) {
                float4 o = *(const float4*)&s_act[r * 512 + k];  // uniform broadcast
                acc[r].x = fmaf(o.x, w0.x, acc[r].x); acc[r].y = fmaf(o.x, w0.y, acc[r].y);
                acc[r].x = fmaf(o.y, w1.x, acc[r].x); acc[r].y = fmaf(o.y, w1.y, acc[r].y);
                acc[r].x = fmaf(o.z, w2.x, acc[r].x); acc[r].y = fmaf(o.z, w2.y, acc[r].y);
                acc[r].x = fmaf(o.w, w3.x, acc[r].x); acc[r].y = fmaf(o.w, w3.y, acc[r].y);
            }
        }
        __syncthreads();                 // staging reads done; alias partials
        float2* P2 = (float2*)s_act;     // [8][128] f2 = 8 KB
        if (kg == 1) {
            #pragma unroll
            for (int r = 0; r < 8; ++r) P2[r * 128 + c2l] = acc[r];
        }
        __syncthreads();
        if (kg == 0) {
            float2 bb = ((const float2*)b1)[c2g];
            float* F = ws + FEAT_OFF;
            #pragma unroll
            for (int r = 0; r < 8; ++r) {
                float2 p = P2[r * 128 + c2l];
                float2 v;
                v.x = fmaxf(acc[r].x + p.x + bb.x, 0.f);
                v.y = fmaxf(acc[r].y + p.y + bb.y, 0.f);
                *(float2*)&F[(size_t)(m0 + r) * 512 + c2g * 2] = v;
            }
        }
    } else if (bid < 1024) {
        // ---- gates = h @ WhhT + b_hh: 8 rows x 128 j (jb slice), 2-way kg ----
        const int m0 = ((bid - 512) >> 1) * 8;
        const int jb = bid & 1;
        for (int i = tid; i < 512; i += 256) {
            int r = i >> 6, kq = i & 63;
            *(float4*)&s_act[r * 256 + kq * 4] =
                *(const float4*)&hmem[(size_t)(m0 + r) * 256 + kq * 4];
        }
        __syncthreads();
        const float4* __restrict__ Q = (const float4*)(ws + WHHQ_OFF);  // [256][256]
        const int jl = tid & 127;
        const int kg = tid >> 7;            // 0/1, wave-uniform
        const int j  = jb * 128 + jl;
        const int k0 = kg * 128;
        float ar[8], az[8], an[8];
        #pragma unroll
        for (int r = 0; r < 8; ++r) { ar[r] = 0.f; az[r] = 0.f; an[r] = 0.f; }
        #pragma unroll 4
        for (int k4 = 0; k4 < 32; ++k4) {
            const int k = k0 + k4 * 4;
            float4 q0 = Q[(k + 0) * 256 + j];
            float4 q1 = Q[(k + 1) * 256 + j];
            float4 q2 = Q[(k + 2) * 256 + j];
            float4 q3 = Q[(k + 3) * 256 + j];
            #pragma unroll
            for (int r = 0; r < 8; ++r) {
                float4 h = *(const float4*)&s_act[r * 256 + k];  // uniform broadcast
                ar[r] = fmaf(h.x, q0.x, ar[r]); az[r] = fmaf(h.x, q0.y, az[r]); an[r] = fmaf(h.x, q0.z, an[r]);
                ar[r] = fmaf(h.y, q1.x, ar[r]); az[r] = fmaf(h.y, q1.y, az[r]); an[r] = fmaf(h.y, q1.z, an[r]);
                ar[r] = fmaf(h.z, q2.x, ar[r]); az[r] = fmaf(h.z, q2.y, az[r]); an[r] = fmaf(h.z, q2.z, an[r]);
                ar[r] = fmaf(h.w, q3.x, ar[r]); az[r] = fmaf(h.w, q3.y, az[r]); an[r] = fmaf(h.w, q3.z, an[r]);
            }
        }
        __syncthreads();                 // staging reads done; alias partials
        float* P = s_act;                // [3][8][128] = 12 KB
        if (kg == 1) {
            #pragma unroll
            for (int r = 0; r < 8; ++r) {
                P[(0 * 8 + r) * 128 + jl] = ar[r];
                P[(1 * 8 + r) * 128 + jl] = az[r];
                P[(2 * 8 + r) * 128 + jl] = an[r];
            }
        }
        __syncthreads();
        if (kg == 0) {
            float br = bhh[j], bz = bhh[HM + j], bn = bhh[2 * HM + j];
            float* G = ws + GATES_OFF;
            #pragma unroll
            for (int r = 0; r < 8; ++r) {
                size_t base = (size_t)(m0 + r) * 768 + j;
                G[base]       = ar[r] + P[(0 * 8 + r) * 128 + jl] + br;
                G[base + 256] = az[r] + P[(1 * 8 + r) * 128 + jl] + bz;
                G[base + 512] = an[r] + P[(2 * 8 + r) * 128 + jl] + bn;
            }
        }
    } else {
        // ---- hterm = K2LE*(h @ WcT + bc): 8 rows x 128 cols, 2-way kg ----
        const int m0 = (bid - 1024) * 8;
        for (int i = tid; i < 512; i += 256) {
            int r = i >> 6, kq = i & 63;
            *(float4*)&s_act[r * 256 + kq * 4] =
                *(const float4*)&hmem[(size_t)(m0 + r) * 256 + kq * 4];
        }
        __syncthreads();
        const float* __restrict__ Wt = ws + WCT_OFF;   // [256][128]
        const int c  = tid & 127;
        const int kg = tid >> 7;            // 0/1, wave-uniform
        const int k0 = kg * 128;
        float acc[8];
        #pragma unroll
        for (int r = 0; r < 8; ++r) acc[r] = 0.f;
        #pragma unroll 4
        for (int k4 = 0; k4 < 32; ++k4) {
            const int k = k0 + k4 * 4;
            float w0 = Wt[(k + 0) * 128 + c];
            float w1 = Wt[(k + 1) * 128 + c];
            float w2 = Wt[(k + 2) * 128 + c];
            float w3 = Wt[(k + 3) * 128 + c];
            #pragma unroll
            for (int r = 0; r < 8; ++r) {
                float4 h = *(const float4*)&s_act[r * 256 + k];
                acc[r] = fmaf(h.x, w0, acc[r]); acc[r] = fmaf(h.y, w1, acc[r]);
                acc[r] = fmaf(h.z, w2, acc[r]); acc[r] = fmaf(h.w, w3, acc[r]);
            }
        }
        __syncthreads();
        float* P = s_act;                // [8][128] = 4 KB
        if (kg == 1) {
            #pragma unroll
            for (int r = 0; r < 8; ++r) P[r * 128 + c] = acc[r];
        }
        __syncthreads();
        if (kg == 0) {
            float bb = bc[c];
            float* H = ws + HTERM_OFF;
            #pragma unroll
            for (int r = 0; r < 8; ++r)
                H[(size_t)(m0 + r) * 128 + c] = K2LE * (acc[r] + P[r * 128 + c] + bb);
        }
    }
}

// ---- attention: tanh ctx + softmax + dset -> x; 4 rows/block, grid 512 ----
__global__ __launch_bounds__(512) void attn_kernel(
    const float* __restrict__ obs, const float* __restrict__ Wc,
    const float* __restrict__ Wa,  const float* __restrict__ ba,
    float* __restrict__ ws)
{
    __shared__ float s_obs[4][512];
    __shared__ float s_ht[4][128];
    __shared__ float s_alog[4][512];
    __shared__ float s_wc0[128], s_wa2[128];

    const int tid = threadIdx.x;
    const int row0 = blockIdx.x * 4;
    const float* hterm = ws + HTERM_OFF;
    float* X = ws + X_OFF;

    {
        int r = tid >> 7, kq = tid & 127;
        *(float4*)&s_obs[r][kq * 4] =
            *(const float4*)&obs[(size_t)(row0 + r) * 512 + kq * 4];
    }
    if (tid < 128) {
        int r = tid >> 5, kq = tid & 31;
        *(float4*)&s_ht[r][kq * 4] =
            *(const float4*)&hterm[(size_t)(row0 + r) * 128 + kq * 4];
    } else if (tid < 256) {
        int t = tid - 128;
        s_wc0[t] = K2LE * Wc[t * (HM + 1)];
        s_wa2[t] = 2.0f * Wa[t];
    }
    __syncthreads();

    {
        const float ba0 = ba[0];
        const int o = tid;
        float ob[4], acA[4];
        #pragma unroll
        for (int r = 0; r < 4; ++r) { ob[r] = s_obs[r][o]; acA[r] = 0.f; }
        float swa = 0.f;
        for (int c = 0; c < 128; c += 4) {
            float4 v = *(const float4*)&s_wa2[c];
            swa += v.x + v.y + v.z + v.w;
        }
        swa *= 0.5f;
        for (int c4 = 0; c4 < 32; ++c4) {
            float4 wc = *(const float4*)&s_wc0[c4 * 4];
            float4 wa = *(const float4*)&s_wa2[c4 * 4];
            #pragma unroll
            for (int r = 0; r < 4; ++r) {
                float4 ht = *(const float4*)&s_ht[r][c4 * 4];
                float t0 = fmaf(ob[r], wc.x, ht.x);
                acA[r] = fmaf(wa.x, RCPF(EXP2F(t0) + 1.f), acA[r]);
                float t1 = fmaf(ob[r], wc.y, ht.y);
                acA[r] = fmaf(wa.y, RCPF(EXP2F(t1) + 1.f), acA[r]);
                float t2 = fmaf(ob[r], wc.z, ht.z);
                acA[r] = fmaf(wa.z, RCPF(EXP2F(t2) + 1.f), acA[r]);
                float t3 = fmaf(ob[r], wc.w, ht.w);
                acA[r] = fmaf(wa.w, RCPF(EXP2F(t3) + 1.f), acA[r]);
            }
        }
        #pragma unroll
        for (int r = 0; r < 4; ++r) s_alog[r][o] = ba0 + swa - acA[r];
    }
    __syncthreads();

    {
        const int wv = tid >> 6, lane = tid & 63;
        if (wv < 4) {
            const int r = wv;
            float m = -1e30f;
            for (int o = lane; o < 512; o += 64) m = fmaxf(m, s_alog[r][o]);
            #pragma unroll
            for (int d = 32; d >= 1; d >>= 1) m = fmaxf(m, __shfl_xor(m, d));
            float se = 0.f, sw = 0.f;
            for (int o = lane; o < 512; o += 64) {
                float e = __expf(s_alog[r][o] - m);
                se += e; sw += e * s_obs[r][o];
            }
            #pragma unroll
            for (int d = 32; d >= 1; d >>= 1) { se += __shfl_xor(se, d); sw += __shfl_xor(sw, d); }
            if (lane == 0) X[row0 + r] = sw / se;
        }
    }
}

// ---- out2 GEMM: 8 rows x 128 cols (f2), 4-way cross-wave kg, col-split x4 ----
// grid 1024: bid = rowb*4 + colb; 256 threads
__global__ __launch_bounds__(256) void out2_gemm(
    const float* __restrict__ hmem,  const float* __restrict__ W_ih,
    const float* __restrict__ b_ih,  const float* __restrict__ b2,
    float* __restrict__ ws)
{
    __shared__ float s_act[8 * 768];   // 24 KB; partials aliased after GEMM
    const int tid = threadIdx.x;
    const int rowb = blockIdx.x >> 2, colb = blockIdx.x & 3;
    const int m0 = rowb * 8;
    const float* F = ws + FEAT_OFF;
    const float* G = ws + GATES_OFF;
    const float* X = ws + X_OFF;

    // stage feat rows into [r][0..512)
    for (int i = tid; i < 1024; i += 256) {
        int r = i >> 7, kq = i & 127;
        *(float4*)&s_act[r * 768 + kq * 4] =
            *(const float4*)&F[(size_t)(m0 + r) * 512 + kq * 4];
    }
    // GRU finish -> [r][512..768)
    for (int i = tid; i < 2048; i += 256) {
        int r = i >> 8, j = i & 255;
        int grow = m0 + r;
        float g0 = G[(size_t)grow * 768 + j];
        float g1 = G[(size_t)grow * 768 + 256 + j];
        float g2 = G[(size_t)grow * 768 + 512 + j];
        float hp = hmem[(size_t)grow * 256 + j];
        float x  = X[grow];
        float rg = fast_sig(fmaf(x, W_ih[j], b_ih[j]) + g0);
        float zg = fast_sig(fmaf(x, W_ih[256 + j], b_ih[256 + j]) + g1);
        float ng = fast_tanh(fmaf(x, W_ih[512 + j], b_ih[512 + j]) + rg * g2);
        s_act[r * 768 + 512 + j] = (1.0f - zg) * ng + zg * hp;
    }
    __syncthreads();

    // 4 waves = 4 kg k-slices (192 each); lane owns f2 col within 64-f2 group
    const float2* __restrict__ Wt = (const float2*)(ws + W2T_OFF);  // [768][256 f2]
    const int c2l = tid & 63;
    const int kg  = tid >> 6;            // 0..3, wave-uniform
    const int c2g = colb * 64 + c2l;     // global f2 col [0,256)
    const int k0  = kg * 192;
    float2 acc[8];
    #pragma unroll
    for (int r = 0; r < 8; ++r) acc[r] = make_float2(0.f, 0.f);
    #pragma unroll 4
    for (int k4 = 0; k4 < 48; ++k4) {
        const int k = k0 + k4 * 4;
        float2 w0 = Wt[(k + 0) * 256 + c2g];
        float2 w1 = Wt[(k + 1) * 256 + c2g];
        float2 w2 = Wt[(k + 2) * 256 + c2g];
        float2 w3 = Wt[(k + 3) * 256 + c2g];
        #pragma unroll
        for (int r = 0; r < 8; ++r) {
            float4 o = *(const float4*)&s_act[r * 768 + k];  // uniform broadcast
            acc[r].x = fmaf(o.x, w0.x, acc[r].x); acc[r].y = fmaf(o.x, w0.y, acc[r].y);
            acc[r].x = fmaf(o.y, w1.x, acc[r].x); acc[r].y = fmaf(o.y, w1.y, acc[r].y);
            acc[r].x = fmaf(o.z, w2.x, acc[r].x); acc[r].y = fmaf(o.z, w2.y, acc[r].y);
            acc[r].x = fmaf(o.w, w3.x, acc[r].x); acc[r].y = fmaf(o.w, w3.y, acc[r].y);
        }
    }
    __syncthreads();                    // all GEMM reads done; alias partials
    float2* P2 = (float2*)s_act;        // [3][8][64] f2 = 12 KB
    if (kg != 0) {
        #pragma unroll
        for (int r = 0; r < 8; ++r) P2[((kg - 1) * 8 + r) * 64 + c2l] = acc[r];
    }
    __syncthreads();
    if (kg == 0) {
        float2 bb = ((const float2*)b2)[c2g];
        float* O = ws + OUT2_OFF;
        #pragma unroll
        for (int r = 0; r < 8; ++r) {
            float2 p0 = P2[(0 * 8 + r) * 64 + c2l];
            float2 p1 = P2[(1 * 8 + r) * 64 + c2l];
            float2 p2 = P2[(2 * 8 + r) * 64 + c2l];
            float2 v;
            v.x = fmaxf(acc[r].x + p0.x + p1.x + p2.x + bb.x, 0.f);
            v.y = fmaxf(acc[r].y + p0.y + p1.y + p2.y + bb.y, 0.f);
            *(float2*)&O[(size_t)(m0 + r) * 512 + c2g * 2] = v;
        }
    }
}

// ---- heads + categorical sampling; wave per row, 8 rows/block ----
__global__ __launch_bounds__(512) void heads_kernel(
    const float* __restrict__ Wact,  const float* __restrict__ bact,
    const float* __restrict__ Wcrit, const float* __restrict__ bcrit,
    const float* __restrict__ ws,    float* __restrict__ out)
{
    const int wv = threadIdx.x >> 6, lane = threadIdx.x & 63;
    const int grow = blockIdx.x * 8 + wv;
    const float* o2 = ws + OUT2_OFF;

    float4 x0 = *(const float4*)&o2[(size_t)grow * 512 + lane * 8];
    float4 x1 = *(const float4*)&o2[(size_t)grow * 512 + lane * 8 + 4];

    float la[ACT];
    #pragma unroll
    for (int a = 0; a < ACT; ++a) {
        const float4* wa4 = (const float4*)&Wact[a * HS2 + lane * 8];
        float4 w0 = wa4[0], w1 = wa4[1];
        float p = x0.x * w0.x + x0.y * w0.y + x0.z * w0.z + x0.w * w0.w
                + x1.x * w1.x + x1.y * w1.y + x1.z * w1.z + x1.w * w1.w;
        #pragma unroll
        for (int d = 32; d >= 1; d >>= 1) p += __shfl_xor(p, d);
        la[a] = p + bact[a];
    }
    const float4* wc4 = (const float4*)&Wcrit[lane * 8];
    float4 w0 = wc4[0], w1 = wc4[1];
    float pv = x0.x * w0.x + x0.y * w0.y + x0.z * w0.z + x0.w * w0.w
             + x1.x * w1.x + x1.y * w1.y + x1.z * w1.z + x1.w * w1.w;
    #pragma unroll
    for (int d = 32; d >= 1; d >>= 1) pv += __shfl_xor(pv, d);

    float g = (lane < ACT) ? gumbel_ra(grow, lane) : 0.0f;
    float best = -1e30f; int amax = 0;
    float mx = -1e30f;
    #pragma unroll
    for (int a = 0; a < ACT; ++a) {
        float g_ = __shfl(g, a);
        float y = la[a] + g_;
        if (y > best) { best = y; amax = a; }   // first-max tie-break
        mx = fmaxf(mx, la[a]);
    }
    float se = 0.f;
    #pragma unroll
    for (int a = 0; a < ACT; ++a) se += __expf(la[a] - mx);
    float lse = mx + logf(se);
    float lp = la[amax] - lse;
    if (lane == 0) {
        out[grow]          = (float)amax;
        out[NW + grow]     = pv + bcrit[0];
        out[2 * NW + grow] = lp;
    }
}

extern "C" void kernel_launch(void* const* d_in, const int* in_sizes, int n_in,
                              void* d_out, int out_size, void* d_ws, size_t ws_size,
                              hipStream_t stream) {
    const float* obs   = (const float*)d_in[0];
    const float* hmem  = (const float*)d_in[1];
    const float* W1    = (const float*)d_in[2];
    const float* b1    = (const float*)d_in[3];
    const float* Wc    = (const float*)d_in[4];
    const float* bc    = (const float*)d_in[5];
    const float* Wa    = (const float*)d_in[6];
    const float* ba    = (const float*)d_in[7];
    const float* W_ih  = (const float*)d_in[8];
    const float* b_ih  = (const float*)d_in[9];
    const float* W_hh  = (const float*)d_in[10];
    const float* b_hh  = (const float*)d_in[11];
    const float* W2    = (const float*)d_in[12];
    const float* b2    = (const float*)d_in[13];
    const float* Wact  = (const float*)d_in[14];
    const float* bact  = (const float*)d_in[15];
    const float* Wcrit = (const float*)d_in[16];
    const float* bcrit = (const float*)d_in[17];
    float* ws = (float*)d_ws;

    transpose_weights<<<736, 256, 0, stream>>>(W1, Wc, W_hh, W2, ws);
    gemm8v2<<<1280, 256, 0, stream>>>(obs, hmem, b1, bc, b_hh, ws);
    attn_kernel<<<512, 512, 0, stream>>>(obs, Wc, Wa, ba, ws);
    out2_gemm<<<1024, 256, 0, stream>>>(hmem, W_ih, b_ih, b2, ws);
    heads_kernel<<<256, 512, 0, stream>>>(Wact, bact, Wcrit, bcrit, ws, (float*)d_out);
}